// Round 1
// baseline (5406.063 us; speedup 1.0000x reference)
//
#include <hip/hip_runtime.h>
#include <hip/hip_bf16.h>

// Problem constants
#define SEQ    70
#define BATCH  128
#define HID    512
#define EMB    512
#define VOCAB  10000
#define VPAD   10112            // VOCAB padded to multiple of 128
#define MROWS  (SEQ*BATCH)      // 8960
#define LOGITS_ELEMS (89600000) // SEQ*BATCH*VOCAB

typedef float  floatx4 __attribute__((ext_vector_type(4)));
typedef short  shortx8 __attribute__((ext_vector_type(8)));

__device__ __forceinline__ unsigned short f2b(float f) {
    unsigned int u = __builtin_bit_cast(unsigned int, f);
    unsigned int r = (u + 0x7fff + ((u >> 16) & 1)) >> 16;   // RNE
    return (unsigned short)r;
}
__device__ __forceinline__ float sigmoidf_(float x) { return 1.f / (1.f + __expf(-x)); }

// ---------------------------------------------------------------------------
// transpose + fp32->bf16 convert:  src (512 x C) -> dst (Npad x 512), pad rows = 0
__global__ void transpose_conv(const float* __restrict__ src, unsigned short* __restrict__ dst,
                               int C, int Npad) {
    __shared__ float tile[32][33];
    int r0 = blockIdx.x * 32, c0 = blockIdx.y * 32;
    int tx = threadIdx.x, ty = threadIdx.y;       // tx 0..31, ty 0..7
    #pragma unroll
    for (int i = 0; i < 32; i += 8) {
        int r = r0 + ty + i, c = c0 + tx;
        tile[ty + i][tx] = (c < C) ? src[(size_t)r * C + c] : 0.f;
    }
    __syncthreads();
    #pragma unroll
    for (int i = 0; i < 32; i += 8) {
        int dr = c0 + ty + i;      // dest row = source col
        int dc = r0 + tx;          // dest col = source row
        dst[(size_t)dr * 512 + dc] = f2b(tile[tx][ty + i]);
    }
}

// embedding gather + convert: E[t*128+b][e] = bf16(emb[idx[t*128+b]][e])
__global__ void gather_conv(const int* __restrict__ idx, const float* __restrict__ emb,
                            unsigned short* __restrict__ E) {
    int row = blockIdx.x;
    int t = threadIdx.x;                     // 128 threads, 4 floats each
    int id = idx[row];
    const float4 v = *(const float4*)&emb[(size_t)id * EMB + t * 4];
    ushort4 o;
    o.x = f2b(v.x); o.y = f2b(v.y); o.z = f2b(v.z); o.w = f2b(v.w);
    *(ushort4*)&E[(size_t)row * EMB + t * 4] = o;
}

__global__ void hinit(const float* __restrict__ hid, float* __restrict__ h0, float* __restrict__ h1) {
    int i = blockIdx.x * 256 + threadIdx.x;
    h0[i] = hid[i];
    h1[i] = hid[65536 + i];
}

__global__ void tail_copy(const float* __restrict__ h0, const float* __restrict__ h1,
                          float* __restrict__ out) {
    int i = blockIdx.x * 256 + threadIdx.x;   // 131072 threads
    out[LOGITS_ELEMS + i] = (i < 65536) ? h0[i] : h1[i - 65536];
}

// ---------------------------------------------------------------------------
// bf16 MFMA GEMM (m97 recipe): C[M x Nlog] = A[M x 512] * Bt[Npad x 512]^T + bias
// tile 128x128, 4 waves, BK=32, global_load_lds width 16, single-buffer 2-barrier.
__global__ __launch_bounds__(256) void gemm_bt(const unsigned short* __restrict__ A,
                                               const unsigned short* __restrict__ Bt,
                                               const float* __restrict__ bias,
                                               float* __restrict__ C,
                                               int Nlog, int ldc) {
    constexpr int K = 512;
    __shared__ __align__(16) unsigned short As[128 * 32];
    __shared__ __align__(16) unsigned short Bs[128 * 32];
    int m0 = blockIdx.x * 128, n0 = blockIdx.y * 128;
    int tid = threadIdx.x, lane = tid & 63, w = tid >> 6;
    int wm = w >> 1, wn = w & 1;
    int quad = lane >> 4, l16 = lane & 15;
    floatx4 acc[4][4] = {};

    for (int kc = 0; kc < K; kc += 32) {
        #pragma unroll
        for (int j = 0; j < 2; ++j) {          // A tile: 128 rows x 32 k (8 KB)
            int chunk = j * 256 + tid;         // 16-byte chunks, 4 per row
            int row = chunk >> 2, cc = chunk & 3;
            const unsigned short* g = A + (size_t)(m0 + row) * K + kc + cc * 8;
            unsigned short* l = As + (size_t)(j * 256 + w * 64) * 8;
            __builtin_amdgcn_global_load_lds((__attribute__((address_space(1))) const unsigned int*)g,
                                             (__attribute__((address_space(3))) unsigned int*)l, 16, 0, 0);
        }
        #pragma unroll
        for (int j = 0; j < 2; ++j) {          // B tile: 128 n-rows x 32 k
            int chunk = j * 256 + tid;
            int row = chunk >> 2, cc = chunk & 3;
            const unsigned short* g = Bt + (size_t)(n0 + row) * K + kc + cc * 8;
            unsigned short* l = Bs + (size_t)(j * 256 + w * 64) * 8;
            __builtin_amdgcn_global_load_lds((__attribute__((address_space(1))) const unsigned int*)g,
                                             (__attribute__((address_space(3))) unsigned int*)l, 16, 0, 0);
        }
        __syncthreads();
        shortx8 af[4], bfv[4];
        #pragma unroll
        for (int i = 0; i < 4; ++i)
            af[i] = *(const shortx8*)&As[(wm * 64 + i * 16 + l16) * 32 + quad * 8];
        #pragma unroll
        for (int i = 0; i < 4; ++i)
            bfv[i] = *(const shortx8*)&Bs[(wn * 64 + i * 16 + l16) * 32 + quad * 8];
        #pragma unroll
        for (int i = 0; i < 4; ++i)
            #pragma unroll
            for (int jn = 0; jn < 4; ++jn)
                acc[i][jn] = __builtin_amdgcn_mfma_f32_16x16x32_bf16(af[i], bfv[jn], acc[i][jn], 0, 0, 0);
        __syncthreads();
    }
    // epilogue: C/D layout col=lane&15, row=quad*4+reg
    #pragma unroll
    for (int i = 0; i < 4; ++i) {
        int row = m0 + wm * 64 + i * 16 + quad * 4;
        #pragma unroll
        for (int jn = 0; jn < 4; ++jn) {
            int col = n0 + wn * 64 + jn * 16 + l16;
            if (col < Nlog) {
                float bb = bias ? bias[col] : 0.f;
                #pragma unroll
                for (int r = 0; r < 4; ++r)
                    C[(size_t)(row + r) * ldc + col] = acc[i][jn][r] + bb;
            }
        }
    }
}

// ---------------------------------------------------------------------------
// Small fp32 GEMM core: tile 16(M) x 64(N), K=512, block 256.
// thread: n = tid&63, m0 = (tid>>6)*4, 4 outputs.
#define SGEMM_COMPUTE(ACC)                                           \
    __syncthreads();                                                 \
    _Pragma("unroll")                                                \
    for (int kk = 0; kk < 32; ++kk) {                                \
        float4 a = *(const float4*)&As[kk * 16 + m0];                \
        float  b = Bs[kk * 64 + n];                                  \
        ACC[0] += a.x * b; ACC[1] += a.y * b;                        \
        ACC[2] += a.z * b; ACC[3] += a.w * b;                        \
    }                                                                \
    __syncthreads();

// u0 = h0 @ U_h0  (N=1024), store raw
__global__ __launch_bounds__(256) void k_u0(const float* __restrict__ h0r,
                                            const float* __restrict__ Uh0,
                                            float* __restrict__ u0) {
    __shared__ __align__(16) float As[32 * 16];
    __shared__ __align__(16) float Bs[32 * 64];
    int row0 = blockIdx.x * 16, n0 = blockIdx.y * 64;
    int tid = threadIdx.x, n = tid & 63, m0 = (tid >> 6) * 4;
    float acc[4] = {0.f, 0.f, 0.f, 0.f};
    for (int kc = 0; kc < 512; kc += 32) {
        #pragma unroll
        for (int e0 = 0; e0 < 2; ++e0) {
            int e = tid + e0 * 256, r = e >> 5, kk = e & 31;
            As[kk * 16 + r] = h0r[(row0 + r) * 512 + kc + kk];
        }
        #pragma unroll
        for (int i = 0; i < 8; ++i) {
            int e = tid + i * 256, kk = e >> 6, nn = e & 63;
            Bs[kk * 64 + nn] = Uh0[(size_t)(kc + kk) * 1024 + n0 + nn];
        }
        SGEMM_COMPUTE(acc)
    }
    #pragma unroll
    for (int r = 0; r < 4; ++r)
        u0[(row0 + m0 + r) * 1024 + n0 + n] = acc[r];
}

// v0 = (r0*h0) @ U_ht0 ; h0w = (1-z0)h0 + z0 tanh(G0h + v0)   (N=512)
__global__ __launch_bounds__(256) void k_h0(const float* __restrict__ h0r, float* __restrict__ h0w,
                                            const float* __restrict__ u0, const float* __restrict__ G0,
                                            const float* __restrict__ Uht0, int t) {
    __shared__ __align__(16) float As[32 * 16];
    __shared__ __align__(16) float Bs[32 * 64];
    int row0 = blockIdx.x * 16, n0 = blockIdx.y * 64;
    int tid = threadIdx.x, n = tid & 63, m0 = (tid >> 6) * 4;
    float acc[4] = {0.f, 0.f, 0.f, 0.f};
    for (int kc = 0; kc < 512; kc += 32) {
        #pragma unroll
        for (int e0 = 0; e0 < 2; ++e0) {
            int e = tid + e0 * 256, r = e >> 5, kk = e & 31;
            int b = row0 + r, k = kc + kk;
            float rg = sigmoidf_(G0[(size_t)(t * 128 + b) * 1536 + k] + u0[b * 1024 + k]);
            As[kk * 16 + r] = rg * h0r[b * 512 + k];
        }
        #pragma unroll
        for (int i = 0; i < 8; ++i) {
            int e = tid + i * 256, kk = e >> 6, nn = e & 63;
            Bs[kk * 64 + nn] = Uht0[(size_t)(kc + kk) * 512 + n0 + nn];
        }
        SGEMM_COMPUTE(acc)
    }
    #pragma unroll
    for (int r = 0; r < 4; ++r) {
        int b = row0 + m0 + r, col = n0 + n;
        size_t gi = (size_t)(t * 128 + b) * 1536;
        float z  = sigmoidf_(G0[gi + 512 + col] + u0[b * 1024 + 512 + col]);
        float ht = tanhf(G0[gi + 1024 + col] + acc[r]);
        float ho = h0r[b * 512 + col];
        h0w[b * 512 + col] = (1.f - z) * ho + z * ht;
    }
}

// merged: g1 = h0n@W_x1+b1 (N 0..1535) | u1 = h1r@U_h1 (1536..2559) | u0_next = h0n@U_h0 (2560..3583)
__global__ __launch_bounds__(256) void k_mid(const float* __restrict__ h0n, const float* __restrict__ h1r,
                                             const float* __restrict__ Wx1, const float* __restrict__ Uh1,
                                             const float* __restrict__ Uh0, const float* __restrict__ b1,
                                             float* __restrict__ g1, float* __restrict__ u1,
                                             float* __restrict__ u0) {
    __shared__ __align__(16) float As[32 * 16];
    __shared__ __align__(16) float Bs[32 * 64];
    int row0 = blockIdx.x * 16, n0 = blockIdx.y * 64;
    const float* Ap; const float* Bp; const float* biasp = nullptr;
    float* outp; int ldB, cb, ldo;
    if (n0 < 1536)      { Ap = h0n; Bp = Wx1; ldB = 1536; cb = n0;        outp = g1; ldo = 1536; biasp = b1; }
    else if (n0 < 2560) { Ap = h1r; Bp = Uh1; ldB = 1024; cb = n0 - 1536; outp = u1; ldo = 1024; }
    else                { Ap = h0n; Bp = Uh0; ldB = 1024; cb = n0 - 2560; outp = u0; ldo = 1024; }
    int tid = threadIdx.x, n = tid & 63, m0 = (tid >> 6) * 4;
    float acc[4] = {0.f, 0.f, 0.f, 0.f};
    for (int kc = 0; kc < 512; kc += 32) {
        #pragma unroll
        for (int e0 = 0; e0 < 2; ++e0) {
            int e = tid + e0 * 256, r = e >> 5, kk = e & 31;
            As[kk * 16 + r] = Ap[(row0 + r) * 512 + kc + kk];
        }
        #pragma unroll
        for (int i = 0; i < 8; ++i) {
            int e = tid + i * 256, kk = e >> 6, nn = e & 63;
            Bs[kk * 64 + nn] = Bp[(size_t)(kc + kk) * ldB + cb + nn];
        }
        SGEMM_COMPUTE(acc)
    }
    #pragma unroll
    for (int r = 0; r < 4; ++r) {
        float bb = biasp ? biasp[cb + n] : 0.f;
        outp[(row0 + m0 + r) * ldo + cb + n] = acc[r] + bb;
    }
}

// v1 = (r1*h1) @ U_ht1 ; h1w = (1-z1)h1 + z1 tanh(g1h + v1); also bf16 into H1 (N=512)
__global__ __launch_bounds__(256) void k_h1(const float* __restrict__ h1r, float* __restrict__ h1w,
                                            const float* __restrict__ u1, const float* __restrict__ g1,
                                            const float* __restrict__ Uht1,
                                            unsigned short* __restrict__ H1b, int t) {
    __shared__ __align__(16) float As[32 * 16];
    __shared__ __align__(16) float Bs[32 * 64];
    int row0 = blockIdx.x * 16, n0 = blockIdx.y * 64;
    int tid = threadIdx.x, n = tid & 63, m0 = (tid >> 6) * 4;
    float acc[4] = {0.f, 0.f, 0.f, 0.f};
    for (int kc = 0; kc < 512; kc += 32) {
        #pragma unroll
        for (int e0 = 0; e0 < 2; ++e0) {
            int e = tid + e0 * 256, r = e >> 5, kk = e & 31;
            int b = row0 + r, k = kc + kk;
            float rg = sigmoidf_(g1[b * 1536 + k] + u1[b * 1024 + k]);
            As[kk * 16 + r] = rg * h1r[b * 512 + k];
        }
        #pragma unroll
        for (int i = 0; i < 8; ++i) {
            int e = tid + i * 256, kk = e >> 6, nn = e & 63;
            Bs[kk * 64 + nn] = Uht1[(size_t)(kc + kk) * 512 + n0 + nn];
        }
        SGEMM_COMPUTE(acc)
    }
    #pragma unroll
    for (int r = 0; r < 4; ++r) {
        int b = row0 + m0 + r, col = n0 + n;
        float z  = sigmoidf_(g1[b * 1536 + 512 + col] + u1[b * 1024 + 512 + col]);
        float ht = tanhf(g1[b * 1536 + 1024 + col] + acc[r]);
        float hn = (1.f - z) * h1r[b * 512 + col] + z * ht;
        h1w[b * 512 + col] = hn;
        H1b[(size_t)(t * 128 + b) * 512 + col] = f2b(hn);
    }
}

// ---------------------------------------------------------------------------
extern "C" void kernel_launch(void* const* d_in, const int* in_sizes, int n_in,
                              void* d_out, int out_size, void* d_ws, size_t ws_size,
                              hipStream_t stream) {
    const int*   inputs = (const int*)  d_in[0];
    const float* hidden = (const float*)d_in[1];
    const float* emb    = (const float*)d_in[2];
    const float* Wx0    = (const float*)d_in[3];
    const float* Uh0    = (const float*)d_in[4];
    const float* Uht0   = (const float*)d_in[5];
    const float* b0     = (const float*)d_in[6];
    const float* Wx1    = (const float*)d_in[7];
    const float* Uh1    = (const float*)d_in[8];
    const float* Uht1   = (const float*)d_in[9];
    const float* b1     = (const float*)d_in[10];
    const float* decW   = (const float*)d_in[11];
    const float* decb   = (const float*)d_in[12];
    float* out = (float*)d_out;

    char* ws = (char*)d_ws;
    size_t off = 0;
    auto take = [&](size_t bytes) -> char* {
        char* p = ws + off;
        off += (bytes + 255) & ~(size_t)255;
        return p;
    };
    float*          G0   = (float*)         take((size_t)MROWS * 1536 * 4);  // 55.0 MB
    unsigned short* Eb   = (unsigned short*)take((size_t)MROWS * 512 * 2);   //  9.2 MB
    unsigned short* Wx0t = (unsigned short*)take((size_t)1536 * 512 * 2);    //  1.6 MB
    unsigned short* dWt  = (unsigned short*)take((size_t)VPAD * 512 * 2);    // 10.4 MB
    unsigned short* H1b  = (unsigned short*)take((size_t)MROWS * 512 * 2);   //  9.2 MB
    float* h0a = (float*)take(65536 * 4);
    float* h0b = (float*)take(65536 * 4);
    float* h1a = (float*)take(65536 * 4);
    float* h1b = (float*)take(65536 * 4);
    float* u0  = (float*)take(131072 * 4);
    float* g1  = (float*)take(196608 * 4);
    float* u1  = (float*)take(131072 * 4);

    // setup: weight transposes/converts, gather, h init
    transpose_conv<<<dim3(16, 48),  dim3(32, 8), 0, stream>>>(Wx0,  Wx0t, 1536, 1536);
    transpose_conv<<<dim3(16, 316), dim3(32, 8), 0, stream>>>(decW, dWt, VOCAB, VPAD);
    gather_conv<<<MROWS, 128, 0, stream>>>(inputs, emb, Eb);
    hinit<<<256, 256, 0, stream>>>(hidden, h0a, h1a);

    // G0 = E @ W_x0 + b0  (all timesteps at once)
    gemm_bt<<<dim3(70, 12), 256, 0, stream>>>(Eb, Wx0t, b0, G0, 1536, 1536);

    // prime u0 for t=0
    k_u0<<<dim3(8, 16), 256, 0, stream>>>(h0a, Uh0, u0);

    for (int t = 0; t < 70; ++t) {
        const float* h0r = (t & 1) ? h0b : h0a;  float* h0w = (t & 1) ? h0a : h0b;
        const float* h1r = (t & 1) ? h1b : h1a;  float* h1w = (t & 1) ? h1a : h1b;
        k_h0 <<<dim3(8, 8),  256, 0, stream>>>(h0r, h0w, u0, G0, Uht0, t);
        k_mid<<<dim3(8, 56), 256, 0, stream>>>(h0w, h1r, Wx1, Uh1, Uh0, b1, g1, u1, u0);
        k_h1 <<<dim3(8, 8),  256, 0, stream>>>(h1r, h1w, u1, g1, Uht1, H1b, t);
    }

    // logits = H1 @ dec_W + dec_b   -> d_out
    gemm_bt<<<dim3(70, 79), 256, 0, stream>>>(H1b, dWt, decb, out, VOCAB, VOCAB);

    // final hidden (h0 final in h0a, h1 final in h1a since 70 is even)
    tail_copy<<<512, 256, 0, stream>>>(h0a, h1a, out);
}

// Round 2
// 3576.505 us; speedup vs baseline: 1.5115x; 1.5115x over previous
//
#include <hip/hip_runtime.h>
#include <hip/hip_bf16.h>

// Problem constants
#define SEQ    70
#define BATCH  128
#define HID    512
#define EMB    512
#define VOCAB  10000
#define VPAD   10112            // VOCAB padded to multiple of 128
#define MROWS  (SEQ*BATCH)      // 8960
#define LOGITS_ELEMS (89600000) // SEQ*BATCH*VOCAB

typedef float  floatx4 __attribute__((ext_vector_type(4)));
typedef short  shortx8 __attribute__((ext_vector_type(8)));

__device__ __forceinline__ unsigned short f2b(float f) {
    unsigned int u = __builtin_bit_cast(unsigned int, f);
    unsigned int r = (u + 0x7fff + ((u >> 16) & 1)) >> 16;   // RNE
    return (unsigned short)r;
}
__device__ __forceinline__ void split_bf16(float x, unsigned short& hi, unsigned short& lo) {
    hi = f2b(x);
    float fh = __builtin_bit_cast(float, (unsigned int)hi << 16);
    lo = f2b(x - fh);
}
__device__ __forceinline__ float sigmoidf_(float x) { return 1.f / (1.f + __expf(-x)); }

// ---------------------------------------------------------------------------
// transpose + fp32->bf16 convert:  src (512 x C) -> dst (Npad x 512), pad rows = 0
__global__ void transpose_conv(const float* __restrict__ src, unsigned short* __restrict__ dst,
                               int C, int Npad) {
    __shared__ float tile[32][33];
    int r0 = blockIdx.x * 32, c0 = blockIdx.y * 32;
    int tx = threadIdx.x, ty = threadIdx.y;       // tx 0..31, ty 0..7
    #pragma unroll
    for (int i = 0; i < 32; i += 8) {
        int r = r0 + ty + i, c = c0 + tx;
        tile[ty + i][tx] = (c < C) ? src[(size_t)r * C + c] : 0.f;
    }
    __syncthreads();
    #pragma unroll
    for (int i = 0; i < 32; i += 8) {
        int dr = c0 + ty + i;      // dest row = source col
        int dc = r0 + tx;          // dest col = source row
        dst[(size_t)dr * 512 + dc] = f2b(tile[tx][ty + i]);
    }
}

// transpose + hi/lo split:  src (512 x C) f32 -> dsth/dstl (C x 512) bf16. C multiple of 32.
__global__ void transpose_split(const float* __restrict__ src, unsigned short* __restrict__ dh,
                                unsigned short* __restrict__ dl, int C) {
    __shared__ float tile[32][33];
    int r0 = blockIdx.x * 32, c0 = blockIdx.y * 32;
    int tx = threadIdx.x, ty = threadIdx.y;
    #pragma unroll
    for (int i = 0; i < 32; i += 8)
        tile[ty + i][tx] = src[(size_t)(r0 + ty + i) * C + c0 + tx];
    __syncthreads();
    #pragma unroll
    for (int i = 0; i < 32; i += 8) {
        int dr = c0 + ty + i, dc = r0 + tx;
        unsigned short hi, lo;
        split_bf16(tile[tx][ty + i], hi, lo);
        dh[(size_t)dr * 512 + dc] = hi;
        dl[(size_t)dr * 512 + dc] = lo;
    }
}

// embedding gather + convert
__global__ void gather_conv(const int* __restrict__ idx, const float* __restrict__ emb,
                            unsigned short* __restrict__ E) {
    int row = blockIdx.x;
    int t = threadIdx.x;
    int id = idx[row];
    const float4 v = *(const float4*)&emb[(size_t)id * EMB + t * 4];
    ushort4 o;
    o.x = f2b(v.x); o.y = f2b(v.y); o.z = f2b(v.z); o.w = f2b(v.w);
    *(ushort4*)&E[(size_t)row * EMB + t * 4] = o;
}

__global__ void hinit_split(const float* __restrict__ hid,
                            float* __restrict__ h0f, unsigned short* __restrict__ h0h, unsigned short* __restrict__ h0l,
                            float* __restrict__ h1f, unsigned short* __restrict__ h1h, unsigned short* __restrict__ h1l) {
    int i = blockIdx.x * 256 + threadIdx.x;   // 65536 threads
    float a = hid[i], b = hid[65536 + i];
    unsigned short hi, lo;
    h0f[i] = a; split_bf16(a, hi, lo); h0h[i] = hi; h0l[i] = lo;
    h1f[i] = b; split_bf16(b, hi, lo); h1h[i] = hi; h1l[i] = lo;
}

__global__ void tail_copy(const float* __restrict__ h0, const float* __restrict__ h1,
                          float* __restrict__ out) {
    int i = blockIdx.x * 256 + threadIdx.x;   // 131072 threads
    out[LOGITS_ELEMS + i] = (i < 65536) ? h0[i] : h1[i - 65536];
}

// ---------------------------------------------------------------------------
// bf16 MFMA GEMM (m97 recipe): C[M x Nlog] = A[M x 512] * Bt[Npad x 512]^T + bias
__global__ __launch_bounds__(256) void gemm_bt(const unsigned short* __restrict__ A,
                                               const unsigned short* __restrict__ Bt,
                                               const float* __restrict__ bias,
                                               float* __restrict__ C,
                                               int Nlog, int ldc) {
    constexpr int K = 512;
    __shared__ __align__(16) unsigned short As[128 * 32];
    __shared__ __align__(16) unsigned short Bs[128 * 32];
    int m0 = blockIdx.x * 128, n0 = blockIdx.y * 128;
    int tid = threadIdx.x, lane = tid & 63, w = tid >> 6;
    int wm = w >> 1, wn = w & 1;
    int quad = lane >> 4, l16 = lane & 15;
    floatx4 acc[4][4] = {};

    for (int kc = 0; kc < K; kc += 32) {
        #pragma unroll
        for (int j = 0; j < 2; ++j) {
            int chunk = j * 256 + tid;
            int row = chunk >> 2, cc = chunk & 3;
            const unsigned short* g = A + (size_t)(m0 + row) * K + kc + cc * 8;
            unsigned short* l = As + (size_t)(j * 256 + w * 64) * 8;
            __builtin_amdgcn_global_load_lds((__attribute__((address_space(1))) const unsigned int*)g,
                                             (__attribute__((address_space(3))) unsigned int*)l, 16, 0, 0);
        }
        #pragma unroll
        for (int j = 0; j < 2; ++j) {
            int chunk = j * 256 + tid;
            int row = chunk >> 2, cc = chunk & 3;
            const unsigned short* g = Bt + (size_t)(n0 + row) * K + kc + cc * 8;
            unsigned short* l = Bs + (size_t)(j * 256 + w * 64) * 8;
            __builtin_amdgcn_global_load_lds((__attribute__((address_space(1))) const unsigned int*)g,
                                             (__attribute__((address_space(3))) unsigned int*)l, 16, 0, 0);
        }
        __syncthreads();
        shortx8 af[4], bfv[4];
        #pragma unroll
        for (int i = 0; i < 4; ++i)
            af[i] = *(const shortx8*)&As[(wm * 64 + i * 16 + l16) * 32 + quad * 8];
        #pragma unroll
        for (int i = 0; i < 4; ++i)
            bfv[i] = *(const shortx8*)&Bs[(wn * 64 + i * 16 + l16) * 32 + quad * 8];
        #pragma unroll
        for (int i = 0; i < 4; ++i)
            #pragma unroll
            for (int jn = 0; jn < 4; ++jn)
                acc[i][jn] = __builtin_amdgcn_mfma_f32_16x16x32_bf16(af[i], bfv[jn], acc[i][jn], 0, 0, 0);
        __syncthreads();
    }
    #pragma unroll
    for (int i = 0; i < 4; ++i) {
        int row = m0 + wm * 64 + i * 16 + quad * 4;
        #pragma unroll
        for (int jn = 0; jn < 4; ++jn) {
            int col = n0 + wn * 64 + jn * 16 + l16;
            if (col < Nlog) {
                float bb = bias ? bias[col] : 0.f;
                #pragma unroll
                for (int r = 0; r < 4; ++r)
                    C[(size_t)(row + r) * ldc + col] = acc[i][jn][r] + bb;
            }
        }
    }
}

// ---------------------------------------------------------------------------
// Recurrent GEMM core: per block (256 thr, 4 waves) computes C[64 x 16] over K=512
// with bf16 hi/lo split (3 MFMA products). A pointers pre-offset to the 64-row base;
// B pointers pre-offset to the 16-col tile (N x K layout).
__device__ __forceinline__ floatx4 rgemm64(const unsigned short* __restrict__ Ah,
                                           const unsigned short* __restrict__ Al,
                                           const unsigned short* __restrict__ Bh,
                                           const unsigned short* __restrict__ Bl,
                                           int tid) {
    int lane = tid & 63, w = tid >> 6, l16 = lane & 15, quad = lane >> 4;
    const unsigned short* ah = Ah + (size_t)(w * 16 + l16) * 512 + quad * 8;
    const unsigned short* al = Al + (size_t)(w * 16 + l16) * 512 + quad * 8;
    const unsigned short* bh = Bh + (size_t)l16 * 512 + quad * 8;
    const unsigned short* bl = Bl + (size_t)l16 * 512 + quad * 8;
    floatx4 acc = {};
    #pragma unroll
    for (int ks = 0; ks < 16; ++ks) {
        shortx8 vbh = *(const shortx8*)(bh + ks * 32);
        shortx8 vbl = *(const shortx8*)(bl + ks * 32);
        shortx8 vah = *(const shortx8*)(ah + ks * 32);
        shortx8 val = *(const shortx8*)(al + ks * 32);
        acc = __builtin_amdgcn_mfma_f32_16x16x32_bf16(vah, vbh, acc, 0, 0, 0);
        acc = __builtin_amdgcn_mfma_f32_16x16x32_bf16(val, vbh, acc, 0, 0, 0);
        acc = __builtin_amdgcn_mfma_f32_16x16x32_bf16(vah, vbl, acc, 0, 0, 0);
    }
    return acc;
}

// phase 1: u0 = h0@U_h0 (tiles 0..63) | u1 = h1@U_h1 (tiles 64..127). grid = 256 (M-split 2).
// epilogue: tiles 0..31 -> rh0 = sigmoid(G0r+u0r)*h0 (hi/lo); 32..63 -> z0; 64..127 -> u1 raw.
__global__ __launch_bounds__(256) void k_ph1(
    const unsigned short* __restrict__ h0h, const unsigned short* __restrict__ h0l,
    const unsigned short* __restrict__ h1h, const unsigned short* __restrict__ h1l,
    const float* __restrict__ h0f,
    const unsigned short* __restrict__ Uh0h, const unsigned short* __restrict__ Uh0l,
    const unsigned short* __restrict__ Uh1h, const unsigned short* __restrict__ Uh1l,
    const float* __restrict__ G0, int t,
    unsigned short* __restrict__ rh0h, unsigned short* __restrict__ rh0l,
    float* __restrict__ z0, float* __restrict__ u1) {
    int tid = threadIdx.x;
    int tile = blockIdx.x >> 1, mh = blockIdx.x & 1;
    int lane = tid & 63, w = tid >> 6, l16 = lane & 15, quad = lane >> 4;
    int rb = mh * 64;
    const unsigned short *Ah, *Al, *Bh, *Bl;
    if (tile < 64) { Ah = h0h; Al = h0l; Bh = Uh0h + (size_t)tile * 16 * 512; Bl = Uh0l + (size_t)tile * 16 * 512; }
    else           { Ah = h1h; Al = h1l; Bh = Uh1h + (size_t)(tile - 64) * 16 * 512; Bl = Uh1l + (size_t)(tile - 64) * 16 * 512; }
    floatx4 acc = rgemm64(Ah + (size_t)rb * 512, Al + (size_t)rb * 512, Bh, Bl, tid);
    int rowb = rb + w * 16 + quad * 4;
    if (tile < 32) {
        int col = tile * 16 + l16;
        #pragma unroll
        for (int r = 0; r < 4; ++r) {
            int row = rowb + r;
            float rg = sigmoidf_(G0[(size_t)(t * 128 + row) * 1536 + col] + acc[r]);
            float rh = rg * h0f[row * 512 + col];
            unsigned short hi, lo; split_bf16(rh, hi, lo);
            rh0h[row * 512 + col] = hi; rh0l[row * 512 + col] = lo;
        }
    } else if (tile < 64) {
        int col = (tile - 32) * 16 + l16;
        #pragma unroll
        for (int r = 0; r < 4; ++r) {
            int row = rowb + r;
            z0[row * 512 + col] = sigmoidf_(G0[(size_t)(t * 128 + row) * 1536 + 512 + col] + acc[r]);
        }
    } else {
        int col = (tile - 64) * 16 + l16;
        #pragma unroll
        for (int r = 0; r < 4; ++r) {
            int row = rowb + r;
            u1[row * 1024 + col] = acc[r];
        }
    }
}

// phase 2: v0 = rh0@U_ht0; h0' = (1-z0)h0 + z0 tanh(G0wh + v0). grid = 64.
__global__ __launch_bounds__(256) void k_ph2(
    const unsigned short* __restrict__ rh0h, const unsigned short* __restrict__ rh0l,
    const unsigned short* __restrict__ Uth, const unsigned short* __restrict__ Utl,
    const float* __restrict__ G0, int t, const float* __restrict__ z0,
    const float* __restrict__ h0f_r,
    float* __restrict__ h0f_w, unsigned short* __restrict__ h0h_w, unsigned short* __restrict__ h0l_w) {
    int tid = threadIdx.x;
    int tile = blockIdx.x >> 1, mh = blockIdx.x & 1;
    int lane = tid & 63, w = tid >> 6, l16 = lane & 15, quad = lane >> 4;
    int rb = mh * 64;
    floatx4 acc = rgemm64(rh0h + (size_t)rb * 512, rh0l + (size_t)rb * 512,
                          Uth + (size_t)tile * 16 * 512, Utl + (size_t)tile * 16 * 512, tid);
    int rowb = rb + w * 16 + quad * 4;
    int col = tile * 16 + l16;
    #pragma unroll
    for (int r = 0; r < 4; ++r) {
        int row = rowb + r;
        float ht = tanhf(G0[(size_t)(t * 128 + row) * 1536 + 1024 + col] + acc[r]);
        float z  = z0[row * 512 + col];
        float hn = (1.f - z) * h0f_r[row * 512 + col] + z * ht;
        h0f_w[row * 512 + col] = hn;
        unsigned short hi, lo; split_bf16(hn, hi, lo);
        h0h_w[row * 512 + col] = hi; h0l_w[row * 512 + col] = lo;
    }
}

// phase 3: g1 = h0'@W_x1 + b1. grid = 192. epilogue by col region.
__global__ __launch_bounds__(256) void k_ph3(
    const unsigned short* __restrict__ h0h_n, const unsigned short* __restrict__ h0l_n,
    const unsigned short* __restrict__ Wh, const unsigned short* __restrict__ Wl,
    const float* __restrict__ b1, const float* __restrict__ u1,
    const float* __restrict__ h1f_r,
    unsigned short* __restrict__ rh1h, unsigned short* __restrict__ rh1l,
    float* __restrict__ z1, float* __restrict__ wh1) {
    int tid = threadIdx.x;
    int tile = blockIdx.x >> 1, mh = blockIdx.x & 1;
    int lane = tid & 63, w = tid >> 6, l16 = lane & 15, quad = lane >> 4;
    int rb = mh * 64;
    floatx4 acc = rgemm64(h0h_n + (size_t)rb * 512, h0l_n + (size_t)rb * 512,
                          Wh + (size_t)tile * 16 * 512, Wl + (size_t)tile * 16 * 512, tid);
    int rowb = rb + w * 16 + quad * 4;
    int col = tile * 16 + l16;          // 0..1535
    float bb = b1[col];
    if (col < 512) {
        #pragma unroll
        for (int r = 0; r < 4; ++r) {
            int row = rowb + r;
            float r1 = sigmoidf_(acc[r] + bb + u1[row * 1024 + col]);
            float rh = r1 * h1f_r[row * 512 + col];
            unsigned short hi, lo; split_bf16(rh, hi, lo);
            rh1h[row * 512 + col] = hi; rh1l[row * 512 + col] = lo;
        }
    } else if (col < 1024) {
        int c = col - 512;
        #pragma unroll
        for (int r = 0; r < 4; ++r) {
            int row = rowb + r;
            z1[row * 512 + c] = sigmoidf_(acc[r] + bb + u1[row * 1024 + col]);
        }
    } else {
        int c = col - 1024;
        #pragma unroll
        for (int r = 0; r < 4; ++r) {
            int row = rowb + r;
            wh1[row * 512 + c] = acc[r] + bb;
        }
    }
}

// phase 4: v1 = rh1@U_ht1; h1' = (1-z1)h1 + z1 tanh(wh1 + v1); bf16 into H1. grid = 64.
__global__ __launch_bounds__(256) void k_ph4(
    const unsigned short* __restrict__ rh1h, const unsigned short* __restrict__ rh1l,
    const unsigned short* __restrict__ Uth, const unsigned short* __restrict__ Utl,
    const float* __restrict__ z1, const float* __restrict__ wh1,
    const float* __restrict__ h1f_r,
    float* __restrict__ h1f_w, unsigned short* __restrict__ h1h_w, unsigned short* __restrict__ h1l_w,
    unsigned short* __restrict__ H1b, int t) {
    int tid = threadIdx.x;
    int tile = blockIdx.x >> 1, mh = blockIdx.x & 1;
    int lane = tid & 63, w = tid >> 6, l16 = lane & 15, quad = lane >> 4;
    int rb = mh * 64;
    floatx4 acc = rgemm64(rh1h + (size_t)rb * 512, rh1l + (size_t)rb * 512,
                          Uth + (size_t)tile * 16 * 512, Utl + (size_t)tile * 16 * 512, tid);
    int rowb = rb + w * 16 + quad * 4;
    int col = tile * 16 + l16;
    #pragma unroll
    for (int r = 0; r < 4; ++r) {
        int row = rowb + r;
        float ht = tanhf(wh1[row * 512 + col] + acc[r]);
        float z  = z1[row * 512 + col];
        float hn = (1.f - z) * h1f_r[row * 512 + col] + z * ht;
        h1f_w[row * 512 + col] = hn;
        unsigned short hi, lo; split_bf16(hn, hi, lo);
        h1h_w[row * 512 + col] = hi; h1l_w[row * 512 + col] = lo;
        H1b[(size_t)(t * 128 + row) * 512 + col] = hi;
    }
}

// ---------------------------------------------------------------------------
extern "C" void kernel_launch(void* const* d_in, const int* in_sizes, int n_in,
                              void* d_out, int out_size, void* d_ws, size_t ws_size,
                              hipStream_t stream) {
    const int*   inputs = (const int*)  d_in[0];
    const float* hidden = (const float*)d_in[1];
    const float* emb    = (const float*)d_in[2];
    const float* Wx0    = (const float*)d_in[3];
    const float* Uh0    = (const float*)d_in[4];
    const float* Uht0   = (const float*)d_in[5];
    const float* b0     = (const float*)d_in[6];
    const float* Wx1    = (const float*)d_in[7];
    const float* Uh1    = (const float*)d_in[8];
    const float* Uht1   = (const float*)d_in[9];
    const float* b1     = (const float*)d_in[10];
    const float* decW   = (const float*)d_in[11];
    const float* decb   = (const float*)d_in[12];
    float* out = (float*)d_out;

    char* ws = (char*)d_ws;
    size_t off = 0;
    auto take = [&](size_t bytes) -> char* {
        char* p = ws + off;
        off += (bytes + 255) & ~(size_t)255;
        return p;
    };
    float*          G0   = (float*)         take((size_t)MROWS * 1536 * 4);
    unsigned short* Eb   = (unsigned short*)take((size_t)MROWS * 512 * 2);
    unsigned short* Wx0t = (unsigned short*)take((size_t)1536 * 512 * 2);
    unsigned short* dWt  = (unsigned short*)take((size_t)VPAD * 512 * 2);
    unsigned short* H1b  = (unsigned short*)take((size_t)MROWS * 512 * 2);
    // transposed hi/lo weights (N x 512 bf16)
    unsigned short* Uh0h = (unsigned short*)take(1024 * 512 * 2);
    unsigned short* Uh0l = (unsigned short*)take(1024 * 512 * 2);
    unsigned short* Ut0h = (unsigned short*)take(512 * 512 * 2);
    unsigned short* Ut0l = (unsigned short*)take(512 * 512 * 2);
    unsigned short* Wx1h = (unsigned short*)take(1536 * 512 * 2);
    unsigned short* Wx1l = (unsigned short*)take(1536 * 512 * 2);
    unsigned short* Uh1h = (unsigned short*)take(1024 * 512 * 2);
    unsigned short* Uh1l = (unsigned short*)take(1024 * 512 * 2);
    unsigned short* Ut1h = (unsigned short*)take(512 * 512 * 2);
    unsigned short* Ut1l = (unsigned short*)take(512 * 512 * 2);
    // state (ping-pong)
    float* h0f_a = (float*)take(65536 * 4);  float* h0f_b = (float*)take(65536 * 4);
    float* h1f_a = (float*)take(65536 * 4);  float* h1f_b = (float*)take(65536 * 4);
    unsigned short* h0h_a = (unsigned short*)take(65536 * 2);
    unsigned short* h0h_b = (unsigned short*)take(65536 * 2);
    unsigned short* h0l_a = (unsigned short*)take(65536 * 2);
    unsigned short* h0l_b = (unsigned short*)take(65536 * 2);
    unsigned short* h1h_a = (unsigned short*)take(65536 * 2);
    unsigned short* h1h_b = (unsigned short*)take(65536 * 2);
    unsigned short* h1l_a = (unsigned short*)take(65536 * 2);
    unsigned short* h1l_b = (unsigned short*)take(65536 * 2);
    // per-step scratch
    unsigned short* rh0h = (unsigned short*)take(65536 * 2);
    unsigned short* rh0l = (unsigned short*)take(65536 * 2);
    unsigned short* rh1h = (unsigned short*)take(65536 * 2);
    unsigned short* rh1l = (unsigned short*)take(65536 * 2);
    float* z0  = (float*)take(65536 * 4);
    float* z1  = (float*)take(65536 * 4);
    float* u1  = (float*)take(131072 * 4);
    float* wh1 = (float*)take(65536 * 4);

    // setup
    transpose_conv<<<dim3(16, 48),  dim3(32, 8), 0, stream>>>(Wx0,  Wx0t, 1536, 1536);
    transpose_conv<<<dim3(16, 316), dim3(32, 8), 0, stream>>>(decW, dWt, VOCAB, VPAD);
    transpose_split<<<dim3(16, 32), dim3(32, 8), 0, stream>>>(Uh0,  Uh0h, Uh0l, 1024);
    transpose_split<<<dim3(16, 16), dim3(32, 8), 0, stream>>>(Uht0, Ut0h, Ut0l, 512);
    transpose_split<<<dim3(16, 48), dim3(32, 8), 0, stream>>>(Wx1,  Wx1h, Wx1l, 1536);
    transpose_split<<<dim3(16, 32), dim3(32, 8), 0, stream>>>(Uh1,  Uh1h, Uh1l, 1024);
    transpose_split<<<dim3(16, 16), dim3(32, 8), 0, stream>>>(Uht1, Ut1h, Ut1l, 512);
    gather_conv<<<MROWS, 128, 0, stream>>>(inputs, emb, Eb);
    hinit_split<<<256, 256, 0, stream>>>(hidden, h0f_a, h0h_a, h0l_a, h1f_a, h1h_a, h1l_a);

    // G0 = E @ W_x0 + b0  (all timesteps at once)
    gemm_bt<<<dim3(70, 12), 256, 0, stream>>>(Eb, Wx0t, b0, G0, 1536, 1536);

    for (int t = 0; t < 70; ++t) {
        bool odd = t & 1;
        const float* h0f_r = odd ? h0f_b : h0f_a;  float* h0f_w = odd ? h0f_a : h0f_b;
        const float* h1f_r = odd ? h1f_b : h1f_a;  float* h1f_w = odd ? h1f_a : h1f_b;
        const unsigned short* h0h_r = odd ? h0h_b : h0h_a;  unsigned short* h0h_w = odd ? h0h_a : h0h_b;
        const unsigned short* h0l_r = odd ? h0l_b : h0l_a;  unsigned short* h0l_w = odd ? h0l_a : h0l_b;
        const unsigned short* h1h_r = odd ? h1h_b : h1h_a;  unsigned short* h1h_w = odd ? h1h_a : h1h_b;
        const unsigned short* h1l_r = odd ? h1l_b : h1l_a;  unsigned short* h1l_w = odd ? h1l_a : h1l_b;

        k_ph1<<<256, 256, 0, stream>>>(h0h_r, h0l_r, h1h_r, h1l_r, h0f_r,
                                       Uh0h, Uh0l, Uh1h, Uh1l, G0, t, rh0h, rh0l, z0, u1);
        k_ph2<<<64, 256, 0, stream>>>(rh0h, rh0l, Ut0h, Ut0l, G0, t, z0, h0f_r,
                                      h0f_w, h0h_w, h0l_w);
        k_ph3<<<192, 256, 0, stream>>>(h0h_w, h0l_w, Wx1h, Wx1l, b1, u1, h1f_r,
                                       rh1h, rh1l, z1, wh1);
        k_ph4<<<64, 256, 0, stream>>>(rh1h, rh1l, Ut1h, Ut1l, z1, wh1, h1f_r,
                                      h1f_w, h1h_w, h1l_w, H1b, t);
    }

    // logits = H1 @ dec_W + dec_b   -> d_out
    gemm_bt<<<dim3(70, 79), 256, 0, stream>>>(H1b, dWt, decb, out, VOCAB, VOCAB);

    // final hidden (70 even -> final state in the 'a' set)
    tail_copy<<<512, 256, 0, stream>>>(h0f_a, h1f_a, out);
}